// Round 2
// baseline (1308.906 us; speedup 1.0000x reference)
//
#include <hip/hip_runtime.h>
#include <hip/hip_bf16.h>
#include <math.h>

#define N_NODES 100000
#define N_EDGES 3200000
#define F_IN    1024
#define HID     16
#define N_CLS   40

typedef __attribute__((ext_vector_type(8))) short short8;
typedef __attribute__((ext_vector_type(4))) float floatx4;

// ---------------- Wt build: Wt[c][k] bf16, c in [0,48) = [W1[0] | W1[1] | root1], k in [0,1024)
__global__ void wtrans_k(const float* __restrict__ W1, const float* __restrict__ root1,
                         __hip_bfloat16* __restrict__ Wt) {
    int id = blockIdx.x * 256 + threadIdx.x;
    if (id >= 48 * 1024) return;
    int k = id & 1023, c = id >> 10;
    float v = (c < 16) ? W1[k * HID + c]
            : (c < 32) ? W1[(size_t)F_IN * HID + k * HID + (c - 16)]
                       : root1[k * HID + (c - 32)];
    Wt[(size_t)c * 1024 + k] = __float2bfloat16(v);
}

// ---------------- GEMM1 via MFMA: Y = bf16(x) @ bf16([W1[0]|W1[1]|root1])
// wave = 16 rows x 48 cols; A frags direct from global x (fp32->bf16 in regs);
// B frags direct from global Wt (96 KB, L2-hot). No LDS.
__global__ __launch_bounds__(256) void gemm1_mfma(const float* __restrict__ x,
                                                  const __hip_bfloat16* __restrict__ Wt,
                                                  float* __restrict__ y01,  // (N,32) [y0|y1]
                                                  float* __restrict__ xr)   // (N,16)
{
    int wid = (blockIdx.x * 256 + threadIdx.x) >> 6;
    int lane = threadIdx.x & 63;
    int rowbase = wid * 16;                 // 100000 = 6250*16, exact
    if (rowbase >= N_NODES) return;
    int r = lane & 15, quad = lane >> 4;

    const float* xp = x + (size_t)(rowbase + r) * F_IN + quad * 8;
    const short* w0 = (const short*)Wt + r * 1024 + quad * 8;
    const short* w1 = w0 + 16 * 1024;
    const short* w2 = w0 + 32 * 1024;

    floatx4 acc0 = {0.f, 0.f, 0.f, 0.f};
    floatx4 acc1 = acc0, acc2 = acc0;

#pragma unroll 4
    for (int k = 0; k < F_IN; k += 32) {
        float4 a0 = *(const float4*)(xp + k);
        float4 a1 = *(const float4*)(xp + k + 4);
        union { short8 v; __hip_bfloat162 h[4]; } af;
        af.h[0] = __float22bfloat162_rn(make_float2(a0.x, a0.y));
        af.h[1] = __float22bfloat162_rn(make_float2(a0.z, a0.w));
        af.h[2] = __float22bfloat162_rn(make_float2(a1.x, a1.y));
        af.h[3] = __float22bfloat162_rn(make_float2(a1.z, a1.w));
        short8 b0 = *(const short8*)(w0 + k);
        short8 b1 = *(const short8*)(w1 + k);
        short8 b2 = *(const short8*)(w2 + k);
        acc0 = __builtin_amdgcn_mfma_f32_16x16x32_bf16(af.v, b0, acc0, 0, 0, 0);
        acc1 = __builtin_amdgcn_mfma_f32_16x16x32_bf16(af.v, b1, acc1, 0, 0, 0);
        acc2 = __builtin_amdgcn_mfma_f32_16x16x32_bf16(af.v, b2, acc2, 0, 0, 0);
    }
    // C/D layout: col = lane&15, row = quad*4 + reg
    int row0 = rowbase + quad * 4;
#pragma unroll
    for (int g = 0; g < 4; ++g) {
        size_t rr = (size_t)(row0 + g);
        y01[rr * 32 + r]      = acc0[g];
        y01[rr * 32 + 16 + r] = acc1[g];
        xr[rr * 16 + r]       = acc2[g];
    }
}

// ---------------- Layer-1 push: 16 lanes per edge, msg -> S1[dst], count -> cntf[dst]
__global__ __launch_bounds__(256) void push1_k(const int* __restrict__ ei,
                                               const float* __restrict__ ea,
                                               const float* __restrict__ y01,
                                               float* __restrict__ S1,
                                               float* __restrict__ cntf) {
    int g = blockIdx.x * 256 + threadIdx.x;
    int e = g >> 4;
    if (e >= N_EDGES) return;
    int l = g & 15;
    int s = ei[e], d = ei[N_EDGES + e];
    float p = ea[e];
    float v0 = y01[s * 32 + l];
    float v1 = y01[s * 32 + 16 + l];
    float m = (1.f - p) * v0 + p * v1;
    atomicAdd(&S1[d * 16 + l], m);
    if (l == 0) atomicAdd(&cntf[d], 1.f);
}

// ---------------- x1 = elu(S1/cnt + xr + b1)
__global__ void x1_k(const float* __restrict__ S1, const float* __restrict__ cntf,
                     const float* __restrict__ xr, const float* __restrict__ b1,
                     float* __restrict__ x1) {
    int i = blockIdx.x * 256 + threadIdx.x;
    if (i >= N_NODES * HID) return;
    int node = i >> 4, f = i & 15;
    float v = S1[i] / fmaxf(cntf[node], 1.f) + xr[i] + b1[f];
    x1[i] = v > 0.f ? v : expm1f(v);
}

// ---------------- Layer-2 push: U,V interleaved per node row of 32 floats
__global__ __launch_bounds__(256) void push2_k(const int* __restrict__ ei,
                                               const float* __restrict__ ea,
                                               const float* __restrict__ x1,
                                               float* __restrict__ UV) {
    int g = blockIdx.x * 256 + threadIdx.x;
    int e = g >> 4;
    if (e >= N_EDGES) return;
    int l = g & 15;
    int s = ei[e], d = ei[N_EDGES + e];
    float p = ea[e];
    float v = x1[s * 16 + l];
    atomicAdd(&UV[d * 32 + l], v);
    atomicAdd(&UV[d * 32 + 16 + l], p * v);
}

// ---------------- Final: x2 = ((U-V)@W20 + V@W21)/cnt + x1@root2 + b2; log_softmax
__global__ __launch_bounds__(256) void final_k(const float* __restrict__ x1,
                                               const float* __restrict__ UV,
                                               const float* __restrict__ cntf,
                                               const float* __restrict__ W2,
                                               const float* __restrict__ root2,
                                               const float* __restrict__ b2,
                                               float* __restrict__ out0) {
    int node = (blockIdx.x * 256 + threadIdx.x) >> 6;
    int c = threadIdx.x & 63;
    if (node >= N_NODES) return;
    float val = 0.f;
    if (c < N_CLS) {
        float invc = 1.f / fmaxf(cntf[node], 1.f);
        float s1 = 0.f, s2 = 0.f;
        size_t b16 = (size_t)node * 16, b32 = (size_t)node * 32;
#pragma unroll
        for (int f = 0; f < HID; ++f) {
            float u = UV[b32 + f], vv = UV[b32 + 16 + f], xv = x1[b16 + f];
            s1 += (u - vv) * W2[f * N_CLS + c] + vv * W2[HID * N_CLS + f * N_CLS + c];
            s2 += xv * root2[f * N_CLS + c];
        }
        val = s1 * invc + s2 + b2[c];
    }
    float m = (c < N_CLS) ? val : -INFINITY;
#pragma unroll
    for (int o = 32; o; o >>= 1) m = fmaxf(m, __shfl_xor(m, o));
    float e = (c < N_CLS) ? expf(val - m) : 0.f;
    float ssum = e;
#pragma unroll
    for (int o = 32; o; o >>= 1) ssum += __shfl_xor(ssum, o);
    if (c < N_CLS) out0[(size_t)node * N_CLS + c] = val - m - logf(ssum);
}

extern "C" void kernel_launch(void* const* d_in, const int* in_sizes, int n_in,
                              void* d_out, int out_size, void* d_ws, size_t ws_size,
                              hipStream_t stream) {
    const float* x     = (const float*)d_in[0];
    const int*   ei    = (const int*)d_in[1];
    const float* eattr = (const float*)d_in[2];
    const float* W1    = (const float*)d_in[3];
    const float* root1 = (const float*)d_in[4];
    const float* b1    = (const float*)d_in[5];
    const float* W2    = (const float*)d_in[6];
    const float* root2 = (const float*)d_in[7];
    const float* b2    = (const float*)d_in[8];

    float* out0  = (float*)d_out;                            // (100000,40)
    float* x1out = (float*)d_out + (size_t)N_NODES * N_CLS;  // (100000,16)

    char* w = (char*)d_ws;
    float* y01 = (float*)w;          w += (size_t)N_NODES * 32 * 4;   // 12.8 MB
    float* xr  = (float*)w;          w += (size_t)N_NODES * 16 * 4;   // 6.4 MB
    __hip_bfloat16* Wt = (__hip_bfloat16*)w; w += 48 * 1024 * 2;      // 96 KB
    // contiguous zero region: S1 | cntf | UV
    char* zbase = w;
    float* S1   = (float*)w;         w += (size_t)N_NODES * 16 * 4;   // 6.4 MB
    float* cntf = (float*)w;         w += (size_t)N_NODES * 4;        // 0.4 MB (16B-mult)
    float* UV   = (float*)w;         w += (size_t)N_NODES * 32 * 4;   // 12.8 MB
    size_t zbytes = (size_t)(w - zbase);

    hipMemsetAsync(zbase, 0, zbytes, stream);
    wtrans_k<<<(48 * 1024 + 255) / 256, 256, 0, stream>>>(W1, root1, Wt);
    gemm1_mfma<<<(N_NODES / 16 + 3) / 4, 256, 0, stream>>>(x, Wt, y01, xr);
    push1_k<<<(int)(((size_t)N_EDGES * 16 + 255) / 256), 256, 0, stream>>>(ei, eattr, y01, S1, cntf);
    x1_k<<<(N_NODES * HID + 255) / 256, 256, 0, stream>>>(S1, cntf, xr, b1, x1out);
    push2_k<<<(int)(((size_t)N_EDGES * 16 + 255) / 256), 256, 0, stream>>>(ei, eattr, x1out, UV);
    final_k<<<(N_NODES * 64 + 255) / 256, 256, 0, stream>>>(x1out, UV, cntf, W2, root2, b2, out0);
}

// Round 3
// 1145.601 us; speedup vs baseline: 1.1425x; 1.1425x over previous
//
#include <hip/hip_runtime.h>
#include <hip/hip_bf16.h>
#include <math.h>

#define N_NODES 100000
#define N_EDGES 3200000
#define F_IN    1024
#define HID     16
#define N_CLS   40

typedef __attribute__((ext_vector_type(8))) short short8;
typedef __attribute__((ext_vector_type(4))) float floatx4;

// ---------------- Wt build: Wt[c][k] bf16, c in [0,48) = [W1[0] | W1[1] | root1]
__global__ void wtrans_k(const float* __restrict__ W1, const float* __restrict__ root1,
                         __hip_bfloat16* __restrict__ Wt) {
    int id = blockIdx.x * 256 + threadIdx.x;
    if (id >= 48 * 1024) return;
    int k = id & 1023, c = id >> 10;
    float v = (c < 16) ? W1[k * HID + c]
            : (c < 32) ? W1[(size_t)F_IN * HID + k * HID + (c - 16)]
                       : root1[k * HID + (c - 32)];
    Wt[(size_t)c * 1024 + k] = __float2bfloat16(v);
}

// ---------------- GEMM1 via MFMA. Outputs: y01b (N,16) bf16x2 packed (y0,y1), xr (N,16) fp32
__global__ __launch_bounds__(256) void gemm1_mfma(const float* __restrict__ x,
                                                  const __hip_bfloat16* __restrict__ Wt,
                                                  __hip_bfloat162* __restrict__ y01b,
                                                  float* __restrict__ xr)
{
    int wid = (blockIdx.x * 256 + threadIdx.x) >> 6;
    int lane = threadIdx.x & 63;
    int rowbase = wid * 16;
    if (rowbase >= N_NODES) return;
    int r = lane & 15, quad = lane >> 4;

    const float* xp = x + (size_t)(rowbase + r) * F_IN + quad * 8;
    const short* w0 = (const short*)Wt + r * 1024 + quad * 8;
    const short* w1 = w0 + 16 * 1024;
    const short* w2 = w0 + 32 * 1024;

    floatx4 acc0 = {0.f, 0.f, 0.f, 0.f};
    floatx4 acc1 = acc0, acc2 = acc0;

#pragma unroll 4
    for (int k = 0; k < F_IN; k += 32) {
        float4 a0 = *(const float4*)(xp + k);
        float4 a1 = *(const float4*)(xp + k + 4);
        union { short8 v; __hip_bfloat162 h[4]; } af;
        af.h[0] = __float22bfloat162_rn(make_float2(a0.x, a0.y));
        af.h[1] = __float22bfloat162_rn(make_float2(a0.z, a0.w));
        af.h[2] = __float22bfloat162_rn(make_float2(a1.x, a1.y));
        af.h[3] = __float22bfloat162_rn(make_float2(a1.z, a1.w));
        short8 b0 = *(const short8*)(w0 + k);
        short8 b1 = *(const short8*)(w1 + k);
        short8 b2 = *(const short8*)(w2 + k);
        acc0 = __builtin_amdgcn_mfma_f32_16x16x32_bf16(af.v, b0, acc0, 0, 0, 0);
        acc1 = __builtin_amdgcn_mfma_f32_16x16x32_bf16(af.v, b1, acc1, 0, 0, 0);
        acc2 = __builtin_amdgcn_mfma_f32_16x16x32_bf16(af.v, b2, acc2, 0, 0, 0);
    }
    // C/D layout: col = lane&15, row = quad*4 + reg
    int row0 = rowbase + quad * 4;
#pragma unroll
    for (int g = 0; g < 4; ++g) {
        size_t rr = (size_t)(row0 + g);
        y01b[rr * 16 + r] = __float22bfloat162_rn(make_float2(acc0[g], acc1[g]));
        xr[rr * 16 + r]   = acc2[g];
    }
}

// ---------------- CSR build
__global__ void hist_k(const int* __restrict__ ei, int* __restrict__ counts) {
    int e = blockIdx.x * 256 + threadIdx.x;
    if (e < N_EDGES) atomicAdd(&counts[ei[N_EDGES + e]], 1);
}

__global__ __launch_bounds__(256) void scan1_k(const int* __restrict__ counts,
                                               int* __restrict__ rowptr,
                                               int* __restrict__ partials) {
    __shared__ int sdata[256];
    int t = threadIdx.x;
    int base = blockIdx.x * 1024 + t * 4;
    int v[4];
#pragma unroll
    for (int i = 0; i < 4; ++i) v[i] = (base + i < N_NODES) ? counts[base + i] : 0;
    int tsum = v[0] + v[1] + v[2] + v[3];
    sdata[t] = tsum;
    __syncthreads();
    for (int o = 1; o < 256; o <<= 1) {
        int xv = (t >= o) ? sdata[t - o] : 0;
        __syncthreads();
        sdata[t] += xv;
        __syncthreads();
    }
    int run = sdata[t] - tsum;
#pragma unroll
    for (int i = 0; i < 4; ++i) {
        if (base + i < N_NODES) rowptr[base + i] = run;
        run += v[i];
    }
    if (t == 255) partials[blockIdx.x] = sdata[255];
}

__global__ void scan2_k(int* __restrict__ partials, int nb) {
    __shared__ int s[128];
    int t = threadIdx.x;
    int v = (t < nb) ? partials[t] : 0;
    s[t] = v;
    __syncthreads();
    for (int o = 1; o < 128; o <<= 1) {
        int xv = (t >= o) ? s[t - o] : 0;
        __syncthreads();
        s[t] += xv;
        __syncthreads();
    }
    if (t < nb) partials[t] = s[t] - v;
}

__global__ void scan3_k(int* __restrict__ rowptr, const int* __restrict__ partials,
                        int* __restrict__ fill) {
    int i = blockIdx.x * 256 + threadIdx.x;
    if (i < N_NODES) {
        int r = rowptr[i] + partials[i >> 10];
        rowptr[i] = r;
        fill[i] = r;
    }
    if (i == N_NODES) rowptr[N_NODES] = N_EDGES;
}

__global__ void scatter_k(const int* __restrict__ ei, const float* __restrict__ eattr,
                          int* __restrict__ fill, int* __restrict__ esrc,
                          float* __restrict__ ep) {
    int e = blockIdx.x * 256 + threadIdx.x;
    if (e < N_EDGES) {
        int s = ei[e];
        int d = ei[N_EDGES + e];
        int pos = atomicAdd(&fill[d], 1);
        esrc[pos] = s;
        ep[pos] = eattr[e];
    }
}

// ---------------- Layer-1 pull + ELU (wave per node). Gather = one 4B bf16x2 per lane.
__global__ __launch_bounds__(256) void agg1_k(const __hip_bfloat162* __restrict__ y01b,
                                              const float* __restrict__ xr,
                                              const float* __restrict__ b1,
                                              const int* __restrict__ rowptr,
                                              const int* __restrict__ esrc,
                                              const float* __restrict__ ep,
                                              float* __restrict__ x1out,
                                              __hip_bfloat16* __restrict__ x1b) {
    int wave = (blockIdx.x * 256 + threadIdx.x) >> 6;
    int lane = threadIdx.x & 63;
    if (wave >= N_NODES) return;
    int f = lane & 15, slot = lane >> 4;
    int start = rowptr[wave], end = rowptr[wave + 1];
    float acc = 0.f;
    for (int i = start + slot; i < end; i += 4) {
        int s = esrc[i];
        float p = ep[i];
        __hip_bfloat162 v = y01b[(size_t)s * 16 + f];
        acc += (1.f - p) * __low2float(v) + p * __high2float(v);
    }
    acc += __shfl_xor(acc, 16);
    acc += __shfl_xor(acc, 32);
    float z = acc / fmaxf((float)(end - start), 1.f) + xr[(size_t)wave * 16 + f] + b1[f];
    float x1 = z > 0.f ? z : expm1f(z);
    if (lane < 16) {
        x1out[(size_t)wave * 16 + f] = x1;
        x1b[(size_t)wave * 16 + f] = __float2bfloat16(x1);
    }
}

// ---------------- Layer-2 pull + 16->40 matmul + log_softmax (wave per node, fused)
__global__ __launch_bounds__(256) void agg2f_k(const __hip_bfloat16* __restrict__ x1b,
                                               const float* __restrict__ x1,
                                               const int* __restrict__ rowptr,
                                               const int* __restrict__ esrc,
                                               const float* __restrict__ ep,
                                               const float* __restrict__ W2,
                                               const float* __restrict__ root2,
                                               const float* __restrict__ b2,
                                               float* __restrict__ out0) {
    __shared__ float Us[4][16], Vs[4][16], Xs[4][16];
    int w = threadIdx.x >> 6;
    int node = (blockIdx.x * 256 + threadIdx.x) >> 6;
    int lane = threadIdx.x & 63;
    if (node >= N_NODES) return;   // grid exact: never taken
    int f = lane & 15, slot = lane >> 4;
    int start = rowptr[node], end = rowptr[node + 1];
    float u = 0.f, vv = 0.f;
    for (int i = start + slot; i < end; i += 4) {
        int s = esrc[i];
        float p = ep[i];
        float a = __bfloat162float(x1b[(size_t)s * 16 + f]);
        u += a;
        vv += p * a;
    }
    u += __shfl_xor(u, 16);   u += __shfl_xor(u, 32);
    vv += __shfl_xor(vv, 16); vv += __shfl_xor(vv, 32);
    if (lane < 16) {
        Us[w][f] = u;
        Vs[w][f] = vv;
        Xs[w][f] = x1[(size_t)node * 16 + f];
    }
    __syncthreads();
    float invc = 1.f / fmaxf((float)(end - start), 1.f);
    int c = lane;
    float val = 0.f;
    if (c < N_CLS) {
        float s1 = 0.f, s2 = 0.f;
#pragma unroll
        for (int ff = 0; ff < HID; ++ff) {
            float uu = Us[w][ff], vV = Vs[w][ff];
            s1 += (uu - vV) * W2[ff * N_CLS + c] + vV * W2[HID * N_CLS + ff * N_CLS + c];
            s2 += Xs[w][ff] * root2[ff * N_CLS + c];
        }
        val = s1 * invc + s2 + b2[c];
    }
    float m = (c < N_CLS) ? val : -INFINITY;
#pragma unroll
    for (int o = 32; o; o >>= 1) m = fmaxf(m, __shfl_xor(m, o));
    float e = (c < N_CLS) ? expf(val - m) : 0.f;
    float ss = e;
#pragma unroll
    for (int o = 32; o; o >>= 1) ss += __shfl_xor(ss, o);
    if (c < N_CLS) out0[(size_t)node * N_CLS + c] = val - m - logf(ss);
}

extern "C" void kernel_launch(void* const* d_in, const int* in_sizes, int n_in,
                              void* d_out, int out_size, void* d_ws, size_t ws_size,
                              hipStream_t stream) {
    const float* x     = (const float*)d_in[0];
    const int*   ei    = (const int*)d_in[1];
    const float* eattr = (const float*)d_in[2];
    const float* W1    = (const float*)d_in[3];
    const float* root1 = (const float*)d_in[4];
    const float* b1    = (const float*)d_in[5];
    const float* W2    = (const float*)d_in[6];
    const float* root2 = (const float*)d_in[7];
    const float* b2    = (const float*)d_in[8];

    float* out0  = (float*)d_out;                            // (100000,40)
    float* x1out = (float*)d_out + (size_t)N_NODES * N_CLS;  // (100000,16)

    char* w = (char*)d_ws;
    float* xr            = (float*)w;           w += (size_t)N_NODES * 16 * 4;  // 6.4 MB
    __hip_bfloat162* y01b = (__hip_bfloat162*)w; w += (size_t)N_NODES * 16 * 4; // 6.4 MB
    __hip_bfloat16* x1b  = (__hip_bfloat16*)w;  w += (size_t)N_NODES * 16 * 2;  // 3.2 MB
    __hip_bfloat16* Wt   = (__hip_bfloat16*)w;  w += 48 * 1024 * 2;             // 96 KB
    int*   counts = (int*)w;   w += (size_t)N_NODES * 4;
    int*   rowptr = (int*)w;   w += (size_t)(N_NODES + 4) * 4;
    int*   fill   = (int*)w;   w += (size_t)N_NODES * 4;
    int*   parts  = (int*)w;   w += 1024;
    int*   esrc   = (int*)w;   w += (size_t)N_EDGES * 4;
    float* ep     = (float*)w; w += (size_t)N_EDGES * 4;

    const int NB_SCAN = (N_NODES + 1023) / 1024;  // 98

    hipMemsetAsync(counts, 0, N_NODES * sizeof(int), stream);
    wtrans_k<<<(48 * 1024 + 255) / 256, 256, 0, stream>>>(W1, root1, Wt);
    gemm1_mfma<<<(N_NODES / 16 + 3) / 4, 256, 0, stream>>>(x, Wt, y01b, xr);
    hist_k<<<(N_EDGES + 255) / 256, 256, 0, stream>>>(ei, counts);
    scan1_k<<<NB_SCAN, 256, 0, stream>>>(counts, rowptr, parts);
    scan2_k<<<1, 128, 0, stream>>>(parts, NB_SCAN);
    scan3_k<<<(N_NODES + 256) / 256, 256, 0, stream>>>(rowptr, parts, fill);
    scatter_k<<<(N_EDGES + 255) / 256, 256, 0, stream>>>(ei, eattr, fill, esrc, ep);
    agg1_k<<<N_NODES * 64 / 256, 256, 0, stream>>>(y01b, xr, b1, rowptr, esrc, ep, x1out, x1b);
    agg2f_k<<<N_NODES * 64 / 256, 256, 0, stream>>>(x1b, x1out, rowptr, esrc, ep, W2, root2, b2, out0);
}

// Round 4
// 1107.386 us; speedup vs baseline: 1.1820x; 1.0345x over previous
//
#include <hip/hip_runtime.h>
#include <hip/hip_bf16.h>
#include <math.h>

#define N_NODES 100000
#define N_EDGES 3200000
#define F_IN    1024
#define HID     16
#define N_CLS   40

typedef __attribute__((ext_vector_type(8))) short short8;
typedef __attribute__((ext_vector_type(4))) float floatx4;

// ---------------- Wt build: Wt[c][k] bf16, c in [0,48) = [W1[0] | W1[1] | root1]
__global__ void wtrans_k(const float* __restrict__ W1, const float* __restrict__ root1,
                         __hip_bfloat16* __restrict__ Wt) {
    int id = blockIdx.x * 256 + threadIdx.x;
    if (id >= 48 * 1024) return;
    int k = id & 1023, c = id >> 10;
    float v = (c < 16) ? W1[k * HID + c]
            : (c < 32) ? W1[(size_t)F_IN * HID + k * HID + (c - 16)]
                       : root1[k * HID + (c - 32)];
    Wt[(size_t)c * 1024 + k] = __float2bfloat16(v);
}

// ---------------- GEMM1 via MFMA. Outputs: y01b (N,16) bf16x2 packed (y0,y1), xr (N,16) fp32
__global__ __launch_bounds__(256) void gemm1_mfma(const float* __restrict__ x,
                                                  const __hip_bfloat16* __restrict__ Wt,
                                                  __hip_bfloat162* __restrict__ y01b,
                                                  float* __restrict__ xr)
{
    int wid = (blockIdx.x * 256 + threadIdx.x) >> 6;
    int lane = threadIdx.x & 63;
    int rowbase = wid * 16;
    if (rowbase >= N_NODES) return;
    int r = lane & 15, quad = lane >> 4;

    const float* xp = x + (size_t)(rowbase + r) * F_IN + quad * 8;
    const short* w0 = (const short*)Wt + r * 1024 + quad * 8;
    const short* w1 = w0 + 16 * 1024;
    const short* w2 = w0 + 32 * 1024;

    floatx4 acc0 = {0.f, 0.f, 0.f, 0.f};
    floatx4 acc1 = acc0, acc2 = acc0;

#pragma unroll 4
    for (int k = 0; k < F_IN; k += 32) {
        float4 a0 = *(const float4*)(xp + k);
        float4 a1 = *(const float4*)(xp + k + 4);
        union { short8 v; __hip_bfloat162 h[4]; } af;
        af.h[0] = __float22bfloat162_rn(make_float2(a0.x, a0.y));
        af.h[1] = __float22bfloat162_rn(make_float2(a0.z, a0.w));
        af.h[2] = __float22bfloat162_rn(make_float2(a1.x, a1.y));
        af.h[3] = __float22bfloat162_rn(make_float2(a1.z, a1.w));
        short8 b0 = *(const short8*)(w0 + k);
        short8 b1 = *(const short8*)(w1 + k);
        short8 b2 = *(const short8*)(w2 + k);
        acc0 = __builtin_amdgcn_mfma_f32_16x16x32_bf16(af.v, b0, acc0, 0, 0, 0);
        acc1 = __builtin_amdgcn_mfma_f32_16x16x32_bf16(af.v, b1, acc1, 0, 0, 0);
        acc2 = __builtin_amdgcn_mfma_f32_16x16x32_bf16(af.v, b2, acc2, 0, 0, 0);
    }
    int row0 = rowbase + quad * 4;
#pragma unroll
    for (int g = 0; g < 4; ++g) {
        size_t rr = (size_t)(row0 + g);
        y01b[rr * 16 + r] = __float22bfloat162_rn(make_float2(acc0[g], acc1[g]));
        xr[rr * 16 + r]   = acc2[g];
    }
}

// ---------------- CSR build (int4 reads, packed 8B edge records)
__global__ void hist_k(const int* __restrict__ dst, int* __restrict__ counts) {
    int t = blockIdx.x * 256 + threadIdx.x;          // N_EDGES/4 threads exact
    int4 d = ((const int4*)dst)[t];
    atomicAdd(&counts[d.x], 1);
    atomicAdd(&counts[d.y], 1);
    atomicAdd(&counts[d.z], 1);
    atomicAdd(&counts[d.w], 1);
}

__global__ __launch_bounds__(256) void scan1_k(const int* __restrict__ counts,
                                               int* __restrict__ rowptr,
                                               int* __restrict__ partials) {
    __shared__ int sdata[256];
    int t = threadIdx.x;
    int base = blockIdx.x * 1024 + t * 4;
    int v[4];
#pragma unroll
    for (int i = 0; i < 4; ++i) v[i] = (base + i < N_NODES) ? counts[base + i] : 0;
    int tsum = v[0] + v[1] + v[2] + v[3];
    sdata[t] = tsum;
    __syncthreads();
    for (int o = 1; o < 256; o <<= 1) {
        int xv = (t >= o) ? sdata[t - o] : 0;
        __syncthreads();
        sdata[t] += xv;
        __syncthreads();
    }
    int run = sdata[t] - tsum;
#pragma unroll
    for (int i = 0; i < 4; ++i) {
        if (base + i < N_NODES) rowptr[base + i] = run;
        run += v[i];
    }
    if (t == 255) partials[blockIdx.x] = sdata[255];
}

__global__ void scan2_k(int* __restrict__ partials, int nb) {
    __shared__ int s[128];
    int t = threadIdx.x;
    int v = (t < nb) ? partials[t] : 0;
    s[t] = v;
    __syncthreads();
    for (int o = 1; o < 128; o <<= 1) {
        int xv = (t >= o) ? s[t - o] : 0;
        __syncthreads();
        s[t] += xv;
        __syncthreads();
    }
    if (t < nb) partials[t] = s[t] - v;
}

__global__ void scan3_k(int* __restrict__ rowptr, const int* __restrict__ partials,
                        int* __restrict__ fill) {
    int i = blockIdx.x * 256 + threadIdx.x;
    if (i < N_NODES) {
        int r = rowptr[i] + partials[i >> 10];
        rowptr[i] = r;
        fill[i] = r;
    }
    if (i == N_NODES) rowptr[N_NODES] = N_EDGES;
}

__global__ void scatter_k(const int* __restrict__ ei, const float* __restrict__ eattr,
                          int* __restrict__ fill, uint2* __restrict__ erec) {
    int t = blockIdx.x * 256 + threadIdx.x;          // N_EDGES/4 threads exact
    int4 s4 = ((const int4*)ei)[t];
    int4 d4 = ((const int4*)(ei + N_EDGES))[t];
    float4 p4 = ((const float4*)eattr)[t];
    int pos;
    pos = atomicAdd(&fill[d4.x], 1); erec[pos] = make_uint2((unsigned)s4.x, __float_as_uint(p4.x));
    pos = atomicAdd(&fill[d4.y], 1); erec[pos] = make_uint2((unsigned)s4.y, __float_as_uint(p4.y));
    pos = atomicAdd(&fill[d4.z], 1); erec[pos] = make_uint2((unsigned)s4.z, __float_as_uint(p4.z));
    pos = atomicAdd(&fill[d4.w], 1); erec[pos] = make_uint2((unsigned)s4.w, __float_as_uint(p4.w));
}

// ---------------- Layer-1 pull + ELU. 4 lanes/edge x 16B gather, 16 edge slots/wave.
__global__ __launch_bounds__(256) void agg1_k(const __hip_bfloat162* __restrict__ y01b,
                                              const float* __restrict__ xr,
                                              const float* __restrict__ b1,
                                              const int* __restrict__ rowptr,
                                              const uint2* __restrict__ erec,
                                              float* __restrict__ x1out,
                                              __hip_bfloat16* __restrict__ x1b) {
    int wave = (blockIdx.x * 256 + threadIdx.x) >> 6;
    int lane = threadIdx.x & 63;
    if (wave >= N_NODES) return;
    int q = lane & 3, slot = lane >> 2;   // feature quad (f=q*4..q*4+3), 16 slots
    int start = rowptr[wave], end = rowptr[wave + 1];
    float acc[4] = {0.f, 0.f, 0.f, 0.f};
#pragma unroll 2
    for (int i = start + slot; i < end; i += 16) {
        uint2 rec = erec[i];
        float p = __uint_as_float(rec.y);
        union { uint4 u; __hip_bfloat162 h[4]; } g;
        g.u = *(const uint4*)(y01b + (size_t)rec.x * 16 + q * 4);
#pragma unroll
        for (int j = 0; j < 4; ++j)
            acc[j] += (1.f - p) * __low2float(g.h[j]) + p * __high2float(g.h[j]);
    }
#pragma unroll
    for (int off = 4; off < 64; off <<= 1)
#pragma unroll
        for (int j = 0; j < 4; ++j) acc[j] += __shfl_xor(acc[j], off);
    if (slot == 0) {
        float invc = 1.f / fmaxf((float)(end - start), 1.f);
        float4 xrv = *(const float4*)(xr + (size_t)wave * 16 + q * 4);
        float4 b1v = *(const float4*)(b1 + q * 4);
        float4 o;
        union { ushort4 s; __hip_bfloat16 h[4]; } ob;
        float z;
        z = acc[0] * invc + xrv.x + b1v.x; o.x = z > 0.f ? z : expm1f(z); ob.h[0] = __float2bfloat16(o.x);
        z = acc[1] * invc + xrv.y + b1v.y; o.y = z > 0.f ? z : expm1f(z); ob.h[1] = __float2bfloat16(o.y);
        z = acc[2] * invc + xrv.z + b1v.z; o.z = z > 0.f ? z : expm1f(z); ob.h[2] = __float2bfloat16(o.z);
        z = acc[3] * invc + xrv.w + b1v.w; o.w = z > 0.f ? z : expm1f(z); ob.h[3] = __float2bfloat16(o.w);
        *(float4*)(x1out + (size_t)wave * 16 + q * 4) = o;
        *(ushort4*)((unsigned short*)x1b + (size_t)wave * 16 + q * 4) = ob.s;
    }
}

// ---------------- Layer-2 pull + 16->40 matmul + log_softmax. 4 lanes/edge x 8B gather.
__global__ __launch_bounds__(256) void agg2f_k(const __hip_bfloat16* __restrict__ x1b,
                                               const float* __restrict__ x1,
                                               const int* __restrict__ rowptr,
                                               const uint2* __restrict__ erec,
                                               const float* __restrict__ W2,
                                               const float* __restrict__ root2,
                                               const float* __restrict__ b2,
                                               float* __restrict__ out0) {
    __shared__ float Us[4][16], Vs[4][16], Xs[4][16];
    int w = threadIdx.x >> 6;
    int node = (blockIdx.x * 256 + threadIdx.x) >> 6;
    int lane = threadIdx.x & 63;
    if (node >= N_NODES) return;   // grid exact
    int q = lane & 3, slot = lane >> 2;
    int start = rowptr[node], end = rowptr[node + 1];
    float u[4] = {0.f, 0.f, 0.f, 0.f}, v[4] = {0.f, 0.f, 0.f, 0.f};
#pragma unroll 2
    for (int i = start + slot; i < end; i += 16) {
        uint2 rec = erec[i];
        float p = __uint_as_float(rec.y);
        union { uint2 u2; __hip_bfloat162 h[2]; } g;
        g.u2 = *(const uint2*)((const unsigned short*)x1b + (size_t)rec.x * 16 + q * 4);
        float a0 = __low2float(g.h[0]), a1 = __high2float(g.h[0]);
        float a2 = __low2float(g.h[1]), a3 = __high2float(g.h[1]);
        u[0] += a0; u[1] += a1; u[2] += a2; u[3] += a3;
        v[0] += p * a0; v[1] += p * a1; v[2] += p * a2; v[3] += p * a3;
    }
#pragma unroll
    for (int off = 4; off < 64; off <<= 1)
#pragma unroll
        for (int j = 0; j < 4; ++j) {
            u[j] += __shfl_xor(u[j], off);
            v[j] += __shfl_xor(v[j], off);
        }
    if (slot == 0) {
        ((float4*)Us[w])[q] = make_float4(u[0], u[1], u[2], u[3]);
        ((float4*)Vs[w])[q] = make_float4(v[0], v[1], v[2], v[3]);
        ((float4*)Xs[w])[q] = *(const float4*)(x1 + (size_t)node * 16 + q * 4);
    }
    __syncthreads();
    float invc = 1.f / fmaxf((float)(end - start), 1.f);
    int c = lane;
    float val = 0.f;
    if (c < N_CLS) {
        float s1 = 0.f, s2 = 0.f;
#pragma unroll
        for (int ff = 0; ff < HID; ++ff) {
            float uu = Us[w][ff], vV = Vs[w][ff];
            s1 += (uu - vV) * W2[ff * N_CLS + c] + vV * W2[HID * N_CLS + ff * N_CLS + c];
            s2 += Xs[w][ff] * root2[ff * N_CLS + c];
        }
        val = s1 * invc + s2 + b2[c];
    }
    float m = (c < N_CLS) ? val : -INFINITY;
#pragma unroll
    for (int o = 32; o; o >>= 1) m = fmaxf(m, __shfl_xor(m, o));
    float e = (c < N_CLS) ? expf(val - m) : 0.f;
    float ss = e;
#pragma unroll
    for (int o = 32; o; o >>= 1) ss += __shfl_xor(ss, o);
    if (c < N_CLS) out0[(size_t)node * N_CLS + c] = val - m - logf(ss);
}

extern "C" void kernel_launch(void* const* d_in, const int* in_sizes, int n_in,
                              void* d_out, int out_size, void* d_ws, size_t ws_size,
                              hipStream_t stream) {
    const float* x     = (const float*)d_in[0];
    const int*   ei    = (const int*)d_in[1];
    const float* eattr = (const float*)d_in[2];
    const float* W1    = (const float*)d_in[3];
    const float* root1 = (const float*)d_in[4];
    const float* b1    = (const float*)d_in[5];
    const float* W2    = (const float*)d_in[6];
    const float* root2 = (const float*)d_in[7];
    const float* b2    = (const float*)d_in[8];

    float* out0  = (float*)d_out;                            // (100000,40)
    float* x1out = (float*)d_out + (size_t)N_NODES * N_CLS;  // (100000,16)

    char* w = (char*)d_ws;
    float* xr             = (float*)w;           w += (size_t)N_NODES * 16 * 4;  // 6.4 MB
    __hip_bfloat162* y01b = (__hip_bfloat162*)w; w += (size_t)N_NODES * 16 * 4;  // 6.4 MB
    __hip_bfloat16* x1b   = (__hip_bfloat16*)w;  w += (size_t)N_NODES * 16 * 2;  // 3.2 MB
    __hip_bfloat16* Wt    = (__hip_bfloat16*)w;  w += 48 * 1024 * 2;             // 96 KB
    int*   counts = (int*)w;   w += (size_t)N_NODES * 4;
    int*   rowptr = (int*)w;   w += (size_t)(N_NODES + 4) * 4;
    int*   fill   = (int*)w;   w += (size_t)N_NODES * 4;
    int*   parts  = (int*)w;   w += 1024;
    uint2* erec   = (uint2*)w; w += (size_t)N_EDGES * 8;                          // 25.6 MB

    const int NB_SCAN = (N_NODES + 1023) / 1024;  // 98

    hipMemsetAsync(counts, 0, N_NODES * sizeof(int), stream);
    wtrans_k<<<(48 * 1024 + 255) / 256, 256, 0, stream>>>(W1, root1, Wt);
    gemm1_mfma<<<(N_NODES / 16 + 3) / 4, 256, 0, stream>>>(x, Wt, y01b, xr);
    hist_k<<<N_EDGES / 4 / 256, 256, 0, stream>>>(ei + N_EDGES, counts);
    scan1_k<<<NB_SCAN, 256, 0, stream>>>(counts, rowptr, parts);
    scan2_k<<<1, 128, 0, stream>>>(parts, NB_SCAN);
    scan3_k<<<(N_NODES + 256) / 256, 256, 0, stream>>>(rowptr, parts, fill);
    scatter_k<<<N_EDGES / 4 / 256, 256, 0, stream>>>(ei, eattr, fill, erec);
    agg1_k<<<N_NODES * 64 / 256, 256, 0, stream>>>(y01b, xr, b1, rowptr, erec, x1out, x1b);
    agg2f_k<<<N_NODES * 64 / 256, 256, 0, stream>>>(x1b, x1out, rowptr, erec, W2, root2, b2, out0);
}